// Round 10
// baseline (301.573 us; speedup 1.0000x reference)
//
#include <hip/hip_runtime.h>
#include <hip/hip_bf16.h>

#define DIM 128
#define NN 40000
#define NE 640000
#define NBLK ((NN + 255) / 256)   // 157
#define PS (NN * 32)              // panel stride: 1,280,000 bf16 elems = 2.56 MB

// gfx950 bf16 MFMA fragment types (learn_hip m89/m93/m97):
typedef __attribute__((ext_vector_type(8))) short s16x8;   // 8 bf16 in 4 VGPRs
typedef __attribute__((ext_vector_type(4))) float f32x4;
typedef __attribute__((ext_vector_type(4))) unsigned short u16x4;
typedef __attribute__((ext_vector_type(4))) unsigned int u32x4;

__device__ __forceinline__ float bf16_lo(unsigned v) { return __uint_as_float(v << 16); }
__device__ __forceinline__ float bf16_hi(unsigned v) { return __uint_as_float(v & 0xffff0000u); }
__device__ __forceinline__ unsigned short f_to_bf16(float f) {
    unsigned u = __float_as_uint(f);
    u += 0x7fffu + ((u >> 16) & 1u);   // round-to-nearest-even
    return (unsigned short)(u >> 16);
}

__global__ void fill_const_f32(float* __restrict__ out, int n, float v) {
    int i = blockIdx.x * blockDim.x + threadIdx.x;
    if (i < n) out[i] = v;
}

// ---------------- fp32 -> bf16: x into 4 panels [s][N][32] + weights row-major ----
// 8 elems/thread. x: 640,000 groups (2500 blocks); weights: 8192 groups (32 blocks).
__global__ void cvt_all(const float* __restrict__ x, unsigned short* __restrict__ xp,
                        const float* __restrict__ w0, const float* __restrict__ w1,
                        const float* __restrict__ w2, const float* __restrict__ w3,
                        unsigned short* __restrict__ wb) {
    int g = blockIdx.x * blockDim.x + threadIdx.x;
    if (g < 640000) {
        size_t e0 = (size_t)g * 8;
        int n = (int)(e0 >> 7);
        int d = (int)(e0 & 127);
        int s = d >> 5, dp = d & 31;
        f32x4 v1 = *(const f32x4*)(x + e0);
        f32x4 v2 = *(const f32x4*)(x + e0 + 4);
        u16x4 o1, o2;
        o1.x = f_to_bf16(v1.x); o1.y = f_to_bf16(v1.y); o1.z = f_to_bf16(v1.z); o1.w = f_to_bf16(v1.w);
        o2.x = f_to_bf16(v2.x); o2.y = f_to_bf16(v2.y); o2.z = f_to_bf16(v2.z); o2.w = f_to_bf16(v2.w);
        unsigned short* dst = xp + (size_t)s * PS + (size_t)n * 32 + dp;
        *(u16x4*)dst = o1;
        *(u16x4*)(dst + 4) = o2;
    } else {
        int gp = g - 640000;
        if (gp >= 8192) return;
        int m = gp >> 11;                 // matrix 0..3 (2048 groups each)
        const float* src = (m == 0) ? w0 : (m == 1) ? w1 : (m == 2) ? w2 : w3;
        size_t off = (size_t)(gp & 2047) * 8;
        f32x4 v1 = *(const f32x4*)(src + off);
        f32x4 v2 = *(const f32x4*)(src + off + 4);
        u16x4 o1, o2;
        o1.x = f_to_bf16(v1.x); o1.y = f_to_bf16(v1.y); o1.z = f_to_bf16(v1.z); o1.w = f_to_bf16(v1.w);
        o2.x = f_to_bf16(v2.x); o2.y = f_to_bf16(v2.y); o2.z = f_to_bf16(v2.z); o2.w = f_to_bf16(v2.w);
        unsigned short* dst = wb + (size_t)m * 16384 + off;
        *(u16x4*)dst = o1;
        *(u16x4*)(dst + 4) = o2;
    }
}

// ---------------- zero deg + edge_index dtype detection ----------------
__global__ void zero_detect(int* __restrict__ deg, const int* __restrict__ ei,
                            int* __restrict__ flag) {
    int i = blockIdx.x * blockDim.x + threadIdx.x;
    if (i < NN) deg[i] = 0;
    if (blockIdx.x == 0 && threadIdx.x < 64) {
        int w = ei[2 * threadIdx.x + 1];
        unsigned long long m = __ballot(w == 0);
        if (threadIdx.x == 0) *flag = (m == ~0ull) ? 1 : 0;   // 1 = int64 passthrough
    }
}

// ---------------- CSR build ----------------

__global__ void count_deg(const int* __restrict__ ei, const int* __restrict__ fmt,
                          int* __restrict__ deg) {
    int e = blockIdx.x * blockDim.x + threadIdx.x;
    if (e >= NE) return;
    int dst = (*fmt) ? ((const int2*)ei)[NE + e].x : ei[NE + e];
    if ((unsigned)dst < (unsigned)NN) atomicAdd(&deg[dst], 1);
}

__global__ void block_sums(const int* __restrict__ deg, int* __restrict__ bsum) {
    __shared__ int sh[256];
    int i = blockIdx.x * 256 + threadIdx.x;
    sh[threadIdx.x] = (i < NN) ? deg[i] : 0;
    __syncthreads();
    for (int off = 128; off > 0; off >>= 1) {
        if (threadIdx.x < off) sh[threadIdx.x] += sh[threadIdx.x + off];
        __syncthreads();
    }
    if (threadIdx.x == 0) bsum[blockIdx.x] = sh[0];
}

__global__ void scan_bsums(int* __restrict__ bsum, int nb) {
    __shared__ int sh[256];
    int t = threadIdx.x;
    int v = (t < nb) ? bsum[t] : 0;
    sh[t] = v;
    __syncthreads();
    for (int off = 1; off < 256; off <<= 1) {
        int u = (t >= off) ? sh[t - off] : 0;
        __syncthreads();
        sh[t] += u;
        __syncthreads();
    }
    if (t < nb) bsum[t] = sh[t] - v;   // exclusive
}

__global__ void scan_block(const int* __restrict__ deg, const int* __restrict__ bsum,
                           int* __restrict__ row_ptr, int* __restrict__ cursor) {
    __shared__ int sh[256];
    int t = threadIdx.x;
    int i = blockIdx.x * 256 + t;
    int v = (i < NN) ? deg[i] : 0;
    sh[t] = v;
    __syncthreads();
    for (int off = 1; off < 256; off <<= 1) {
        int u = (t >= off) ? sh[t - off] : 0;
        __syncthreads();
        sh[t] += u;
        __syncthreads();
    }
    int excl = sh[t] - v + bsum[blockIdx.x];
    if (i < NN) { row_ptr[i] = excl; cursor[i] = excl; }
    if (i == NN - 1) row_ptr[NN] = excl + v;
}

__global__ void fill_csr(const int* __restrict__ ei, const int* __restrict__ fmt,
                         int* __restrict__ cursor, int* __restrict__ sorted_src) {
    int e = blockIdx.x * blockDim.x + threadIdx.x;
    if (e >= NE) return;
    int src, dst;
    if (*fmt) {
        src = ((const int2*)ei)[e].x;
        dst = ((const int2*)ei)[NE + e].x;
    } else {
        src = ei[e];
        dst = ei[NE + e];
    }
    if ((unsigned)dst >= (unsigned)NN) return;
    int pos = atomicAdd(&cursor[dst], 1);
    if ((unsigned)pos < (unsigned)NE) sorted_src[pos] = src;
}

// ---------------- XCD-sliced mean aggregation ----------------
// slice = blockIdx.x % 4 -> with round-robin block->XCD dispatch, XCD k only
// touches panel k%4 (2.56 MB, L2-resident). Wave: 16 edge slots x 4 lanes x
// 16 B (= 64 B/edge = one 32-dim slice row), unroll x2, 4 shfl-xor rounds.
// 4 nodes per wave, 16 nodes per block; grid = 4 * 2500 = 10000.

__global__ __launch_bounds__(256) void aggregate_sliced(
    const unsigned short* __restrict__ featp,   // panels [4][N][32] bf16
    const int* __restrict__ row_ptr,
    const int* __restrict__ sorted_src,
    unsigned short* __restrict__ meanp) {       // panels [4][N][32] bf16
    int lane = threadIdx.x & 63;
    int wv = threadIdx.x >> 6;
    int s = blockIdx.x & 3;
    int chunk = blockIdx.x >> 2;
    int slot = lane >> 2;    // 0..15
    int q = lane & 3;        // 16 B sub-chunk within 64 B row-slice
    const unsigned short* panel = featp + (size_t)s * PS;

    for (int j = 0; j < 4; ++j) {
        int n = chunk * 16 + wv * 4 + j;
        int start = row_ptr[n], end = row_ptr[n + 1];
        float a[8] = {0.f, 0.f, 0.f, 0.f, 0.f, 0.f, 0.f, 0.f};
        int i = start + slot;
        for (; i + 16 < end; i += 32) {
            int s1 = sorted_src[i];
            int s2 = sorted_src[i + 16];
            u32x4 v1 = *(const u32x4*)(panel + (size_t)s1 * 32 + q * 8);
            u32x4 v2 = *(const u32x4*)(panel + (size_t)s2 * 32 + q * 8);
            a[0] += bf16_lo(v1.x) + bf16_lo(v2.x);
            a[1] += bf16_hi(v1.x) + bf16_hi(v2.x);
            a[2] += bf16_lo(v1.y) + bf16_lo(v2.y);
            a[3] += bf16_hi(v1.y) + bf16_hi(v2.y);
            a[4] += bf16_lo(v1.z) + bf16_lo(v2.z);
            a[5] += bf16_hi(v1.z) + bf16_hi(v2.z);
            a[6] += bf16_lo(v1.w) + bf16_lo(v2.w);
            a[7] += bf16_hi(v1.w) + bf16_hi(v2.w);
        }
        if (i < end) {
            int s1 = sorted_src[i];
            u32x4 v = *(const u32x4*)(panel + (size_t)s1 * 32 + q * 8);
            a[0] += bf16_lo(v.x); a[1] += bf16_hi(v.x);
            a[2] += bf16_lo(v.y); a[3] += bf16_hi(v.y);
            a[4] += bf16_lo(v.z); a[5] += bf16_hi(v.z);
            a[6] += bf16_lo(v.w); a[7] += bf16_hi(v.w);
        }
#pragma unroll
        for (int k = 0; k < 8; ++k) {
            a[k] += __shfl_xor(a[k], 4, 64);
            a[k] += __shfl_xor(a[k], 8, 64);
            a[k] += __shfl_xor(a[k], 16, 64);
            a[k] += __shfl_xor(a[k], 32, 64);
        }
        if (slot == 0) {
            int d = end - start;
            float inv = 1.f / (float)(d > 1 ? d : 1);
            u32x4 o;
            o.x = (unsigned)f_to_bf16(a[0] * inv) | ((unsigned)f_to_bf16(a[1] * inv) << 16);
            o.y = (unsigned)f_to_bf16(a[2] * inv) | ((unsigned)f_to_bf16(a[3] * inv) << 16);
            o.z = (unsigned)f_to_bf16(a[4] * inv) | ((unsigned)f_to_bf16(a[5] * inv) << 16);
            o.w = (unsigned)f_to_bf16(a[6] * inv) | ((unsigned)f_to_bf16(a[7] * inv) << 16);
            *(u32x4*)(meanp + (size_t)s * PS + (size_t)n * 32 + q * 8) = o;
        }
    }
}

// ---------------- SAGE linear: relu(mean@Wl^T + b + self@Wr^T) ----------------
// 64 rows x 16 cols per wave (4 stacked 16x16 tiles); A-frags read directly
// from panels: k-block kb == panel kb, elem offset row*32 + quad*8 (exact
// MFMA A-frag layout). B-frags row-major weights, register-resident. Layouts
// m89/m120-verified: A[m=lane&15][k=quad*8+j]; B=W[col][k..k+7];
// C/D col=lane&15, row=quad*4+reg.

template <bool WRITE_F32>
__global__ __launch_bounds__(256) void sage_gemm_p(
    const unsigned short* __restrict__ meanp,   // panels [4][N][32]
    const unsigned short* __restrict__ featp,   // panels [4][N][32]
    const unsigned short* __restrict__ Wl,      // [128,128] bf16 row-major
    const unsigned short* __restrict__ Wr,
    const float* __restrict__ bias,             // [128] fp32
    void* __restrict__ outv) {                  // fp32 [N,128] or bf16 panels
    int lane = threadIdx.x & 63;
    int wv = threadIdx.x >> 6;
    int quad = lane >> 4;
    int lid = lane & 15;
    int row0 = blockIdx.x * 64;
    int bcol = blockIdx.y * 64 + wv * 16 + lid;

    const unsigned short* wl0 = Wl + (size_t)bcol * DIM + quad * 8;
    const unsigned short* wr0 = Wr + (size_t)bcol * DIM + quad * 8;
    s16x8 bl[4], br[4];
#pragma unroll
    for (int kb = 0; kb < 4; ++kb) {
        bl[kb] = *(const s16x8*)(wl0 + kb * 32);
        br[kb] = *(const s16x8*)(wr0 + kb * 32);
    }

    f32x4 acc[4] = {{0,0,0,0},{0,0,0,0},{0,0,0,0},{0,0,0,0}};
    s16x8 am[2][4], ah[2][4];

    // prologue: tile 0
#pragma unroll
    for (int kb = 0; kb < 4; ++kb) {
        size_t off = (size_t)kb * PS + (size_t)(row0 + lid) * 32 + quad * 8;
        am[0][kb] = *(const s16x8*)(meanp + off);
        ah[0][kb] = *(const s16x8*)(featp + off);
    }
#pragma unroll
    for (int t = 0; t < 4; ++t) {
        int cb = t & 1, nb = (t + 1) & 1;
        if (t < 3) {
#pragma unroll
            for (int kb = 0; kb < 4; ++kb) {
                size_t off = (size_t)kb * PS + (size_t)(row0 + (t + 1) * 16 + lid) * 32 + quad * 8;
                am[nb][kb] = *(const s16x8*)(meanp + off);
                ah[nb][kb] = *(const s16x8*)(featp + off);
            }
        }
#pragma unroll
        for (int kb = 0; kb < 4; ++kb)
            acc[t] = __builtin_amdgcn_mfma_f32_16x16x32_bf16(am[cb][kb], bl[kb], acc[t], 0, 0, 0);
#pragma unroll
        for (int kb = 0; kb < 4; ++kb)
            acc[t] = __builtin_amdgcn_mfma_f32_16x16x32_bf16(ah[cb][kb], br[kb], acc[t], 0, 0, 0);
    }

    float bv = bias[bcol];
#pragma unroll
    for (int t = 0; t < 4; ++t) {
#pragma unroll
        for (int r = 0; r < 4; ++r) {
            int orow = row0 + t * 16 + quad * 4 + r;
            float v = fmaxf(acc[t][r] + bv, 0.f);   // relu
            if (WRITE_F32) {
                ((float*)outv)[(size_t)orow * DIM + bcol] = v;
            } else {
                // h1 in panel layout for the next layer's gather + GEMM
                ((unsigned short*)outv)[(size_t)(bcol >> 5) * PS +
                                        (size_t)orow * 32 + (bcol & 31)] = f_to_bf16(v);
            }
        }
    }
}

// ---------------- launch ----------------

extern "C" void kernel_launch(void* const* d_in, const int* in_sizes, int n_in,
                              void* d_out, int out_size, void* d_ws, size_t ws_size,
                              hipStream_t stream) {
    const float* x   = (const float*)d_in[0];
    const int*   ei  = (const int*)d_in[1];
    const float* W1l = (const float*)d_in[2];
    const float* b1l = (const float*)d_in[3];
    const float* W1r = (const float*)d_in[4];
    const float* W2l = (const float*)d_in[5];
    const float* b2l = (const float*)d_in[6];
    const float* W2r = (const float*)d_in[7];
    float* out = (float*)d_out;

    const int OUT_ELEMS = NN * DIM;        // 5,120,000

    // workspace layout (256B-aligned)
    const size_t OFF_DEG   = 0;            // N ints
    const size_t OFF_ROW   = 163840;       // N+1 ints
    const size_t OFF_BSUM  = 324608;       // NBLK ints
    const size_t OFF_CUR   = 327680;       // N ints
    const size_t OFF_FMT   = 491264;       // 1 int
    const size_t OFF_SRT   = 491520;       // E ints
    const size_t OFF_WB    = 3051520;      // 4 * 16384 bf16
    const size_t OFF_XP    = 3182592;      // 4 panels x [N][32] bf16 = 10,240,000 B
    const size_t OFF_MEANP = 13422592;     // 4 panels
    const size_t OFF_H1P   = 23662592;     // 4 panels
    const size_t NEEDED    = 33902592;

    if (ws_size < NEEDED) {
        fill_const_f32<<<(OUT_ELEMS + 255) / 256, 256, 0, stream>>>(out, OUT_ELEMS, 50.0f);
        return;
    }

    char* ws = (char*)d_ws;
    int* deg     = (int*)(ws + OFF_DEG);
    int* row_ptr = (int*)(ws + OFF_ROW);
    int* bsum    = (int*)(ws + OFF_BSUM);
    int* cursor  = (int*)(ws + OFF_CUR);
    int* fmtflag = (int*)(ws + OFF_FMT);
    int* sorted  = (int*)(ws + OFF_SRT);
    unsigned short* Wb    = (unsigned short*)(ws + OFF_WB);
    unsigned short* xp    = (unsigned short*)(ws + OFF_XP);
    unsigned short* meanp = (unsigned short*)(ws + OFF_MEANP);
    unsigned short* h1p   = (unsigned short*)(ws + OFF_H1P);
    unsigned short* W1lb = Wb;
    unsigned short* W1rb = Wb + 16384;
    unsigned short* W2lb = Wb + 32768;
    unsigned short* W2rb = Wb + 49152;

    // conversions (x -> panels + weights, one launch)
    cvt_all<<<2532, 256, 0, stream>>>(x, xp, W1l, W1r, W2l, W2r, Wb);

    // CSR build
    zero_detect<<<NBLK, 256, 0, stream>>>(deg, ei, fmtflag);
    count_deg<<<(NE + 255) / 256, 256, 0, stream>>>(ei, fmtflag, deg);
    block_sums<<<NBLK, 256, 0, stream>>>(deg, bsum);
    scan_bsums<<<1, 256, 0, stream>>>(bsum, NBLK);
    scan_block<<<NBLK, 256, 0, stream>>>(deg, bsum, row_ptr, cursor);
    fill_csr<<<(NE + 255) / 256, 256, 0, stream>>>(ei, fmtflag, cursor, sorted);

    // layer 1: h1 = relu(mean(x)@W1l^T + b1l + x@W1r^T)   (panel bf16 out)
    aggregate_sliced<<<10000, 256, 0, stream>>>(xp, row_ptr, sorted, meanp);
    sage_gemm_p<false><<<dim3(NN / 64, 2), 256, 0, stream>>>(meanp, xp, W1lb, W1rb, b1l, h1p);

    // layer 2: out = relu(mean(h1)@W2l^T + b2l + h1@W2r^T)   (fp32 out)
    aggregate_sliced<<<10000, 256, 0, stream>>>(h1p, row_ptr, sorted, meanp);
    sage_gemm_p<true><<<dim3(NN / 64, 2), 256, 0, stream>>>(meanp, h1p, W2lb, W2rb, b2l, out);
}

// Round 11
// 245.405 us; speedup vs baseline: 1.2289x; 1.2289x over previous
//
#include <hip/hip_runtime.h>
#include <hip/hip_bf16.h>

#define DIM 128
#define NN 40000
#define NE 640000
#define NBLK ((NN + 255) / 256)   // 157

// gfx950 bf16 MFMA fragment types (learn_hip m89/m93/m97):
typedef __attribute__((ext_vector_type(8))) short s16x8;   // 8 bf16 in 4 VGPRs
typedef __attribute__((ext_vector_type(4))) float f32x4;
typedef __attribute__((ext_vector_type(4))) unsigned short u16x4;
typedef __attribute__((ext_vector_type(4))) unsigned int u32x4;

__device__ __forceinline__ float bf16_lo(unsigned v) { return __uint_as_float(v << 16); }
__device__ __forceinline__ float bf16_hi(unsigned v) { return __uint_as_float(v & 0xffff0000u); }
__device__ __forceinline__ unsigned short f_to_bf16(float f) {
    unsigned u = __float_as_uint(f);
    u += 0x7fffu + ((u >> 16) & 1u);   // round-to-nearest-even
    return (unsigned short)(u >> 16);
}

__global__ void fill_const_f32(float* __restrict__ out, int n, float v) {
    int i = blockIdx.x * blockDim.x + threadIdx.x;
    if (i < n) out[i] = v;
}

// ---------------- fp32 -> bf16: x (5000 blocks) + 4 weights (64 blocks) ----------------
__global__ void cvt_all(const float* __restrict__ x, unsigned short* __restrict__ xb,
                        const float* __restrict__ w0, const float* __restrict__ w1,
                        const float* __restrict__ w2, const float* __restrict__ w3,
                        unsigned short* __restrict__ wb) {
    int b = blockIdx.x;
    const float* src;
    unsigned short* dst;
    size_t i;
    if (b < 5000) {
        src = x; dst = xb;
        i = (size_t)b * 256 + threadIdx.x;           // x: 1,280,000 f32x4 groups
    } else {
        int w = b - 5000;
        int m = w >> 4;                               // matrix 0..3
        src = (m == 0) ? w0 : (m == 1) ? w1 : (m == 2) ? w2 : w3;
        dst = wb + (size_t)m * 16384;
        i = (size_t)(w & 15) * 256 + threadIdx.x;     // 4096 groups per matrix
    }
    f32x4 v = *(const f32x4*)(src + 4 * i);
    u16x4 o;
    o.x = f_to_bf16(v.x); o.y = f_to_bf16(v.y);
    o.z = f_to_bf16(v.z); o.w = f_to_bf16(v.w);
    *(u16x4*)(dst + 4 * i) = o;
}

// ---------------- zero deg + edge_index dtype detection ----------------
// int64 passthrough: odd 32-bit words (high halves, values < 40000) all zero.
__global__ void zero_detect(int* __restrict__ deg, const int* __restrict__ ei,
                            int* __restrict__ flag) {
    int i = blockIdx.x * blockDim.x + threadIdx.x;
    if (i < NN) deg[i] = 0;
    if (blockIdx.x == 0 && threadIdx.x < 64) {
        int w = ei[2 * threadIdx.x + 1];
        unsigned long long m = __ballot(w == 0);
        if (threadIdx.x == 0) *flag = (m == ~0ull) ? 1 : 0;
    }
}

// ---------------- CSR build ----------------

__global__ void count_deg(const int* __restrict__ ei, const int* __restrict__ fmt,
                          int* __restrict__ deg) {
    int e = blockIdx.x * blockDim.x + threadIdx.x;
    if (e >= NE) return;
    int dst = (*fmt) ? ((const int2*)ei)[NE + e].x : ei[NE + e];
    if ((unsigned)dst < (unsigned)NN) atomicAdd(&deg[dst], 1);
}

__global__ void block_sums(const int* __restrict__ deg, int* __restrict__ bsum) {
    __shared__ int sh[256];
    int i = blockIdx.x * 256 + threadIdx.x;
    sh[threadIdx.x] = (i < NN) ? deg[i] : 0;
    __syncthreads();
    for (int off = 128; off > 0; off >>= 1) {
        if (threadIdx.x < off) sh[threadIdx.x] += sh[threadIdx.x + off];
        __syncthreads();
    }
    if (threadIdx.x == 0) bsum[blockIdx.x] = sh[0];
}

__global__ void scan_bsums(int* __restrict__ bsum, int nb) {
    __shared__ int sh[256];
    int t = threadIdx.x;
    int v = (t < nb) ? bsum[t] : 0;
    sh[t] = v;
    __syncthreads();
    for (int off = 1; off < 256; off <<= 1) {
        int u = (t >= off) ? sh[t - off] : 0;
        __syncthreads();
        sh[t] += u;
        __syncthreads();
    }
    if (t < nb) bsum[t] = sh[t] - v;   // exclusive
}

__global__ void scan_block(const int* __restrict__ deg, const int* __restrict__ bsum,
                           int* __restrict__ row_ptr, int* __restrict__ cursor) {
    __shared__ int sh[256];
    int t = threadIdx.x;
    int i = blockIdx.x * 256 + t;
    int v = (i < NN) ? deg[i] : 0;
    sh[t] = v;
    __syncthreads();
    for (int off = 1; off < 256; off <<= 1) {
        int u = (t >= off) ? sh[t - off] : 0;
        __syncthreads();
        sh[t] += u;
        __syncthreads();
    }
    int excl = sh[t] - v + bsum[blockIdx.x];
    if (i < NN) { row_ptr[i] = excl; cursor[i] = excl; }
    if (i == NN - 1) row_ptr[NN] = excl + v;
}

__global__ void fill_csr(const int* __restrict__ ei, const int* __restrict__ fmt,
                         int* __restrict__ cursor, int* __restrict__ sorted_src) {
    int e = blockIdx.x * blockDim.x + threadIdx.x;
    if (e >= NE) return;
    int src, dst;
    if (*fmt) {
        src = ((const int2*)ei)[e].x;
        dst = ((const int2*)ei)[NE + e].x;
    } else {
        src = ei[e];
        dst = ei[NE + e];
    }
    if ((unsigned)dst >= (unsigned)NN) return;
    int pos = atomicAdd(&cursor[dst], 1);
    if ((unsigned)pos < (unsigned)NE) sorted_src[pos] = src;
}

// ---------------- mean aggregation: one 16-lane group per node ----------------
// 4 nodes per wave IN PARALLEL (groups), 16 nodes per block. Each lane owns
// 16 B (8 dims) of its node's row; accumulators ARE the output fragment —
// zero shuffles, zero LDS. Edge loop unrolled x4: index loads batched, then
// 4 independent row-gathers in flight per lane.

__global__ __launch_bounds__(256) void aggregate_g(
    const unsigned short* __restrict__ xin,
    const int* __restrict__ row_ptr,
    const int* __restrict__ sorted_src,
    unsigned short* __restrict__ mean_out) {
    int lane = threadIdx.x & 63;
    int wv = threadIdx.x >> 6;
    int grp = lane >> 4;     // node within wave
    int lid = lane & 15;     // 16 B sub-chunk of the 256 B row
    int n = blockIdx.x * 16 + wv * 4 + grp;
    int start = row_ptr[n], end = row_ptr[n + 1];

    float a[8] = {0.f, 0.f, 0.f, 0.f, 0.f, 0.f, 0.f, 0.f};
    int i = start;
    for (; i + 3 < end; i += 4) {
        int s0 = sorted_src[i];
        int s1 = sorted_src[i + 1];
        int s2 = sorted_src[i + 2];
        int s3 = sorted_src[i + 3];
        u32x4 v0 = *(const u32x4*)(xin + (size_t)s0 * DIM + lid * 8);
        u32x4 v1 = *(const u32x4*)(xin + (size_t)s1 * DIM + lid * 8);
        u32x4 v2 = *(const u32x4*)(xin + (size_t)s2 * DIM + lid * 8);
        u32x4 v3 = *(const u32x4*)(xin + (size_t)s3 * DIM + lid * 8);
        a[0] += bf16_lo(v0.x) + bf16_lo(v1.x) + bf16_lo(v2.x) + bf16_lo(v3.x);
        a[1] += bf16_hi(v0.x) + bf16_hi(v1.x) + bf16_hi(v2.x) + bf16_hi(v3.x);
        a[2] += bf16_lo(v0.y) + bf16_lo(v1.y) + bf16_lo(v2.y) + bf16_lo(v3.y);
        a[3] += bf16_hi(v0.y) + bf16_hi(v1.y) + bf16_hi(v2.y) + bf16_hi(v3.y);
        a[4] += bf16_lo(v0.z) + bf16_lo(v1.z) + bf16_lo(v2.z) + bf16_lo(v3.z);
        a[5] += bf16_hi(v0.z) + bf16_hi(v1.z) + bf16_hi(v2.z) + bf16_hi(v3.z);
        a[6] += bf16_lo(v0.w) + bf16_lo(v1.w) + bf16_lo(v2.w) + bf16_lo(v3.w);
        a[7] += bf16_hi(v0.w) + bf16_hi(v1.w) + bf16_hi(v2.w) + bf16_hi(v3.w);
    }
    for (; i < end; ++i) {
        int s = sorted_src[i];
        u32x4 v = *(const u32x4*)(xin + (size_t)s * DIM + lid * 8);
        a[0] += bf16_lo(v.x); a[1] += bf16_hi(v.x);
        a[2] += bf16_lo(v.y); a[3] += bf16_hi(v.y);
        a[4] += bf16_lo(v.z); a[5] += bf16_hi(v.z);
        a[6] += bf16_lo(v.w); a[7] += bf16_hi(v.w);
    }

    int d = end - start;
    float inv = 1.f / (float)(d > 1 ? d : 1);
    u32x4 o;
    o.x = (unsigned)f_to_bf16(a[0] * inv) | ((unsigned)f_to_bf16(a[1] * inv) << 16);
    o.y = (unsigned)f_to_bf16(a[2] * inv) | ((unsigned)f_to_bf16(a[3] * inv) << 16);
    o.z = (unsigned)f_to_bf16(a[4] * inv) | ((unsigned)f_to_bf16(a[5] * inv) << 16);
    o.w = (unsigned)f_to_bf16(a[6] * inv) | ((unsigned)f_to_bf16(a[7] * inv) << 16);
    *(u32x4*)(mean_out + (size_t)n * DIM + lid * 8) = o;
}

// ---------------- fused SAGE linear: relu(mean@Wl^T + b + h@Wr^T) ----------------
// 64 rows x 16 cols per wave: 4 stacked 16x16 tiles, B-frags loaded once and
// reused 4x, A double-buffered (2 tiles = 16 outstanding 16B loads).
// mfma_f32_16x16x32_bf16 layouts (m89/m120-verified):
//   A: A[m=lane&15][k=quad*8+j]; B = W[col][k..k+7]; C/D: col=lane&15, row=quad*4+reg.

template <bool WRITE_F32>
__global__ __launch_bounds__(256) void sage_gemm(
    const unsigned short* __restrict__ mean,   // [N,128] bf16
    const unsigned short* __restrict__ hself,  // [N,128] bf16
    const unsigned short* __restrict__ Wl,     // [128,128] bf16
    const unsigned short* __restrict__ Wr,
    const float* __restrict__ bias,            // [128] fp32
    void* __restrict__ outv) {
    int lane = threadIdx.x & 63;
    int wv = threadIdx.x >> 6;
    int quad = lane >> 4;
    int lid = lane & 15;
    int row0 = blockIdx.x * 64;
    int bcol = blockIdx.y * 64 + wv * 16 + lid;

    const unsigned short* wl0 = Wl + (size_t)bcol * DIM + quad * 8;
    const unsigned short* wr0 = Wr + (size_t)bcol * DIM + quad * 8;
    s16x8 bl[4], br[4];
#pragma unroll
    for (int kb = 0; kb < 4; ++kb) {
        bl[kb] = *(const s16x8*)(wl0 + kb * 32);
        br[kb] = *(const s16x8*)(wr0 + kb * 32);
    }

    const unsigned short* ap = mean + (size_t)(row0 + lid) * DIM + quad * 8;
    const unsigned short* hp = hself + (size_t)(row0 + lid) * DIM + quad * 8;
    const int TS = 16 * DIM;   // tile row stride in elements

    f32x4 acc[4] = {{0,0,0,0},{0,0,0,0},{0,0,0,0},{0,0,0,0}};
    s16x8 am[2][4], ah[2][4];

    // prologue: tile 0
#pragma unroll
    for (int kb = 0; kb < 4; ++kb) {
        am[0][kb] = *(const s16x8*)(ap + kb * 32);
        ah[0][kb] = *(const s16x8*)(hp + kb * 32);
    }
#pragma unroll
    for (int t = 0; t < 4; ++t) {
        int cb = t & 1, nb = (t + 1) & 1;
        if (t < 3) {
#pragma unroll
            for (int kb = 0; kb < 4; ++kb) {
                am[nb][kb] = *(const s16x8*)(ap + (t + 1) * TS + kb * 32);
                ah[nb][kb] = *(const s16x8*)(hp + (t + 1) * TS + kb * 32);
            }
        }
#pragma unroll
        for (int kb = 0; kb < 4; ++kb)
            acc[t] = __builtin_amdgcn_mfma_f32_16x16x32_bf16(am[cb][kb], bl[kb], acc[t], 0, 0, 0);
#pragma unroll
        for (int kb = 0; kb < 4; ++kb)
            acc[t] = __builtin_amdgcn_mfma_f32_16x16x32_bf16(ah[cb][kb], br[kb], acc[t], 0, 0, 0);
    }

    float bv = bias[bcol];
#pragma unroll
    for (int t = 0; t < 4; ++t) {
#pragma unroll
        for (int r = 0; r < 4; ++r) {
            int orow = row0 + t * 16 + quad * 4 + r;
            float v = fmaxf(acc[t][r] + bv, 0.f);   // relu
            if (WRITE_F32)
                ((float*)outv)[(size_t)orow * DIM + bcol] = v;
            else
                ((unsigned short*)outv)[(size_t)orow * DIM + bcol] = f_to_bf16(v);
        }
    }
}

// ---------------- launch ----------------

extern "C" void kernel_launch(void* const* d_in, const int* in_sizes, int n_in,
                              void* d_out, int out_size, void* d_ws, size_t ws_size,
                              hipStream_t stream) {
    const float* x   = (const float*)d_in[0];
    const int*   ei  = (const int*)d_in[1];
    const float* W1l = (const float*)d_in[2];
    const float* b1l = (const float*)d_in[3];
    const float* W1r = (const float*)d_in[4];
    const float* W2l = (const float*)d_in[5];
    const float* b2l = (const float*)d_in[6];
    const float* W2r = (const float*)d_in[7];
    float* out = (float*)d_out;

    const int OUT_ELEMS = NN * DIM;        // 5,120,000

    // workspace layout (256B-aligned)
    const size_t OFF_DEG  = 0;             // N ints
    const size_t OFF_ROW  = 163840;        // N+1 ints
    const size_t OFF_BSUM = 324608;        // NBLK ints
    const size_t OFF_CUR  = 327680;        // N ints
    const size_t OFF_FMT  = 491264;        // 1 int
    const size_t OFF_SRT  = 491520;        // E ints
    const size_t OFF_WB   = 3051520;       // 4 * 16384 bf16
    const size_t OFF_XB   = 3182592;       // N*128 bf16
    const size_t OFF_MEAN = 13422592;      // N*128 bf16
    const size_t OFF_H1   = 23662592;      // N*128 bf16
    const size_t NEEDED   = 33902592;

    if (ws_size < NEEDED) {
        fill_const_f32<<<(OUT_ELEMS + 255) / 256, 256, 0, stream>>>(out, OUT_ELEMS, 50.0f);
        return;
    }

    char* ws = (char*)d_ws;
    int* deg     = (int*)(ws + OFF_DEG);
    int* row_ptr = (int*)(ws + OFF_ROW);
    int* bsum    = (int*)(ws + OFF_BSUM);
    int* cursor  = (int*)(ws + OFF_CUR);
    int* fmtflag = (int*)(ws + OFF_FMT);
    int* sorted  = (int*)(ws + OFF_SRT);
    unsigned short* Wb    = (unsigned short*)(ws + OFF_WB);
    unsigned short* xb    = (unsigned short*)(ws + OFF_XB);
    unsigned short* meanb = (unsigned short*)(ws + OFF_MEAN);
    unsigned short* h1b   = (unsigned short*)(ws + OFF_H1);
    unsigned short* W1lb = Wb;
    unsigned short* W1rb = Wb + 16384;
    unsigned short* W2lb = Wb + 32768;
    unsigned short* W2rb = Wb + 49152;

    // conversions (x + all weights, one launch)
    cvt_all<<<5064, 256, 0, stream>>>(x, xb, W1l, W1r, W2l, W2r, Wb);

    // CSR build
    zero_detect<<<NBLK, 256, 0, stream>>>(deg, ei, fmtflag);
    count_deg<<<(NE + 255) / 256, 256, 0, stream>>>(ei, fmtflag, deg);
    block_sums<<<NBLK, 256, 0, stream>>>(deg, bsum);
    scan_bsums<<<1, 256, 0, stream>>>(bsum, NBLK);
    scan_block<<<NBLK, 256, 0, stream>>>(deg, bsum, row_ptr, cursor);
    fill_csr<<<(NE + 255) / 256, 256, 0, stream>>>(ei, fmtflag, cursor, sorted);

    // layer 1: h1 = relu(mean(x)@W1l^T + b1l + x@W1r^T)   (bf16 out)
    aggregate_g<<<NN / 16, 256, 0, stream>>>(xb, row_ptr, sorted, meanb);
    sage_gemm<false><<<dim3(NN / 64, 2), 256, 0, stream>>>(meanb, xb, W1lb, W1rb, b1l, h1b);

    // layer 2: out = relu(mean(h1)@W2l^T + b2l + h1@W2r^T)   (fp32 out)
    aggregate_g<<<NN / 16, 256, 0, stream>>>(h1b, row_ptr, sorted, meanb);
    sage_gemm<true><<<dim3(NN / 64, 2), 256, 0, stream>>>(meanb, h1b, W2lb, W2rb, b2l, out);
}